// Round 20
// baseline (701.503 us; speedup 1.0000x reference)
//
#include <hip/hip_runtime.h>

#define BATCH 32
#define T_LEN 4096
#define NU 64
#define NX 128
#define NY 64
#define KCH 64
#define NC (T_LEN / KCH)
#define KSPLIT 8
#define CHAIN_NB 512   /* persistent chain kernel blocks */

/* workspace float offsets */
#define OFF_E    0            /* becomes A2 */
#define OFF_F    16384        /* becomes A4 */
#define OFF_A    32768
#define OFF_G    49152        /* fallback only */
#define OFF_A8   81920
#define OFF_A16  98304
#define OFF_A32  114688
#define OFF_A64  131072
#define OFF_D    147456       /* D1..D7: 7x64x128 */
#define OFF_P    204800       /* P0..P6: 7x64x64 */
#define OFF_WT   233472       /* 512x576 bf16 */
#define OFF_WF   380928       /* [128][4096] f32 */
#define OFF_WBH  905216
#define OFF_WBL  1167360
#define OFF_XC   1429504
#define OFF_L    1691648      /* fast path: barrier counters live here */
#define OFF_V8   1953792
#define OFF_X8   4050944
#define OFF_UBH  5099520
#define OFF_UBL  9293824
#define OFF_LP   13488128
#define WS_NEED_FLOATS (13488128 + 2097152)

__device__ __forceinline__ int XP(int l)   { return l + ((l >> 3) << 2); }
__device__ __forceinline__ int UP16(int l) { return l + ((l >> 4) << 2); }

__device__ __forceinline__ unsigned short f2bf(float f) {
    unsigned int x = __float_as_uint(f);
    unsigned int r = (x + 0x7FFFu + ((x >> 16) & 1u)) >> 16;
    return (unsigned short)r;
}
__device__ __forceinline__ float bf2f(unsigned short h) {
    return __uint_as_float(((unsigned int)h) << 16);
}
__device__ __forceinline__ float4 f4ms(float4 a, float s, float4 b) {
    float4 r;
    r.x = a.x - s * b.x; r.y = a.y - s * b.y;
    r.z = a.z - s * b.z; r.w = a.w - s * b.w;
    return r;
}
__device__ __forceinline__ float f4dot(float4 a, float4 b) {
    return a.x * b.x + a.y * b.y + a.z * b.z + a.w * b.w;
}
__device__ __forceinline__ void cvt_one(const float* __restrict__ src,
                                        unsigned short* __restrict__ hi,
                                        unsigned short* __restrict__ lo,
                                        size_t idx) {
    float4 v = ((const float4*)src)[idx];
    unsigned short h0 = f2bf(v.x), h1 = f2bf(v.y), h2 = f2bf(v.z), h3 = f2bf(v.w);
    unsigned short l0 = f2bf(v.x - bf2f(h0));
    unsigned short l1 = f2bf(v.y - bf2f(h1));
    unsigned short l2 = f2bf(v.z - bf2f(h2));
    unsigned short l3 = f2bf(v.w - bf2f(h3));
    unsigned long long ph = (unsigned long long)h0 | ((unsigned long long)h1 << 16)
                          | ((unsigned long long)h2 << 32) | ((unsigned long long)h3 << 48);
    unsigned long long pl = (unsigned long long)l0 | ((unsigned long long)l1 << 16)
                          | ((unsigned long long)l2 << 32) | ((unsigned long long)l3 << 48);
    ((unsigned long long*)hi)[idx] = ph;
    ((unsigned long long*)lo)[idx] = pl;
}

typedef __attribute__((ext_vector_type(8))) short bf16x8;
typedef __attribute__((ext_vector_type(4))) float f32x4;

/* ---- K1: E/F build only ---- */
__global__ __launch_bounds__(128) void ef_kernel(const float* __restrict__ M,
                                                 float* __restrict__ E,
                                                 float* __restrict__ F) {
    int part = blockIdx.x >> 7;
    int i = blockIdx.x & 127;
    int j = threadIdx.x;
    const float* Mi2 = M + (size_t)(128 + i) * 256;
    const float* Mj1 = M + (size_t)j * 256;
    if (part == 0) {
        const float* Mi1 = M + (size_t)i * 256;
        const float* Mj2 = M + (size_t)(128 + j) * 256;
        float s11 = 0.f, s22 = 0.f;
        for (int m = 0; m < 256; ++m) {
            s11 += Mi1[m] * Mj1[m];
            s22 += Mi2[m] * Mj2[m];
        }
        float e = 0.5f * (s11 + s22);
        if (i == j) e += 1e-9f;
        E[i * NX + j] = e;
    } else {
        float s21 = 0.f;
        for (int m = 0; m < 256; ++m) s21 += Mi2[m] * Mj1[m];
        F[i * NX + j] = s21;
    }
}

/* ---- K2 (fused): block 0 = R18-verified solve; blocks >=1 = u hi/lo split ---- */
__global__ __launch_bounds__(512, 1) void solvecvt_kernel(const float* __restrict__ E,
                                                          const float* __restrict__ F,
                                                          float* __restrict__ A,
                                                          const float* __restrict__ u,
                                                          unsigned short* __restrict__ hi,
                                                          unsigned short* __restrict__ lo,
                                                          int n4) {
    if (blockIdx.x != 0) {
        if (hi == nullptr) return;
        size_t stride = (size_t)(gridDim.x - 1) * 512;
        for (size_t idx = (size_t)(blockIdx.x - 1) * 512 + threadIdx.x; idx < (size_t)n4;
             idx += stride)
            cvt_one(u, hi, lo, idx);
        return;
    }
    __shared__ __align__(16) float praw[2][4][264];
    __shared__ __align__(16) float4 mrowS[2][128];
    __shared__ float pivarr[128];
    int t = threadIdx.x;
    int rg = t >> 4, seg = t & 15;

    float4 R[4][4];
#pragma unroll
    for (int k = 0; k < 4; ++k) {
        int r = rg + 32 * k;
        const float4* erow = (const float4*)(E + (size_t)r * NX);
        const float4* frow = (const float4*)(F + (size_t)r * NX);
        R[k][0] = erow[seg];
        R[k][1] = erow[seg + 16];
        R[k][2] = frow[seg];
        R[k][3] = frow[seg + 16];
    }
    if (rg < 4) {
        float4* dst = (float4*)&praw[0][rg][0];
        dst[seg]      = R[0][0];
        dst[seg + 16] = R[0][1];
        dst[seg + 32] = R[0][2];
        dst[seg + 48] = R[0][3];
    }
    if (seg == 0) {
#pragma unroll
        for (int k = 0; k < 4; ++k) mrowS[0][rg + 32 * k] = R[k][0];
    }
    __syncthreads();

    int buf = 0;
    for (int wd = 0; wd < 32; ++wd) {
        int k0 = 4 * wd;
        const float* p0s = &praw[buf][0][0];
        const float* p1s = &praw[buf][1][0];
        const float* p2s = &praw[buf][2][0];
        const float* p3s = &praw[buf][3][0];
        float p00 = p0s[k0], p01 = p0s[k0 + 1], p02 = p0s[k0 + 2], p03 = p0s[k0 + 3];
        float r10 = p1s[k0], r11 = p1s[k0 + 1], r12 = p1s[k0 + 2], r13 = p1s[k0 + 3];
        float r20 = p2s[k0], r21 = p2s[k0 + 1], r22 = p2s[k0 + 2], r23 = p2s[k0 + 3];
        float r30 = p3s[k0], r31 = p3s[k0 + 1], r32 = p3s[k0 + 2], r33 = p3s[k0 + 3];
        float inv0 = 1.0f / p00;
        float m1 = r10 * inv0;
        float piv1 = r11 - m1 * p01;
        float inv1 = 1.0f / piv1;
        float p12 = r12 - m1 * p02, p13 = r13 - m1 * p03;
        float m2 = r20 * inv0;
        float m2b = (r21 - m2 * p01) * inv1;
        float piv2 = r22 - m2 * p02 - m2b * p12;
        float inv2 = 1.0f / piv2;
        float p23 = r23 - m2 * p03 - m2b * p13;
        float m3 = r30 * inv0;
        float m3b = (r31 - m3 * p01) * inv1;
        float m3c = (r32 - m3 * p02 - m3b * p12) * inv2;
        float piv3 = r33 - m3 * p03 - m3b * p13 - m3c * p23;
        float inv3 = 1.0f / piv3;
        if (t == 0) {
            pivarr[k0] = p00; pivarr[k0 + 1] = piv1;
            pivarr[k0 + 2] = piv2; pivarr[k0 + 3] = piv3;
        }
        float q0[4], q1[4], q2[4], q3[4];
#pragma unroll
        for (int k = 0; k < 4; ++k) {
            int r = rg + 32 * k;
            float4 mv = mrowS[buf][r];
            int d = r - k0;
            float a = mv.x * inv0;
            if (d == 0) a = 0.f;
            float b2 = (mv.y - a * p01) * inv1;
            if (d == 1) b2 = 0.f;
            float c2 = (mv.z - a * p02 - b2 * p12) * inv2;
            if (d == 2) c2 = 0.f;
            float e2 = (mv.w - a * p03 - b2 * p13 - c2 * p23) * inv3;
            if (d == 3) e2 = 0.f;
            q0[k] = a; q1[k] = b2; q2[k] = c2; q3[k] = e2;
        }
        const float4* w0 = (const float4*)&praw[buf][0][0];
        const float4* w1 = (const float4*)&praw[buf][1][0];
        const float4* w2 = (const float4*)&praw[buf][2][0];
        const float4* w3 = (const float4*)&praw[buf][3][0];
#pragma unroll
        for (int j = 0; j < 4; ++j) {
            int g = seg + 16 * j;
            float4 a0 = w0[g], a1 = w1[g], a2 = w2[g], a3 = w3[g];
            float4 p1v = f4ms(a1, m1, a0);
            float4 p2v = f4ms(f4ms(a2, m2, a0), m2b, p1v);
            float4 p3v = f4ms(f4ms(f4ms(a3, m3, a0), m3b, p1v), m3c, p2v);
#pragma unroll
            for (int k = 0; k < 4; ++k) {
                float4 acc = R[k][j];
                acc = f4ms(acc, q0[k], a0);
                acc = f4ms(acc, q1[k], p1v);
                acc = f4ms(acc, q2[k], p2v);
                acc = f4ms(acc, q3[k], p3v);
                R[k][j] = acc;
            }
        }
        if (wd < 31) {
#pragma unroll
            for (int k = 0; k < 4; ++k) {
                int r = rg + 32 * k;
                int d2 = r - (k0 + 4);
                if (d2 >= 0 && d2 < 4) {
                    float4* dst = (float4*)&praw[buf ^ 1][d2][0];
                    dst[seg]      = R[k][0];
                    dst[seg + 16] = R[k][1];
                    dst[seg + 32] = R[k][2];
                    dst[seg + 48] = R[k][3];
                }
            }
            if (seg == ((wd + 1) & 15)) {
#pragma unroll
                for (int k = 0; k < 4; ++k) {
                    float4 sel = ((wd + 1) < 16) ? R[k][0] : R[k][1];
                    mrowS[buf ^ 1][rg + 32 * k] = sel;
                }
            }
        }
        __syncthreads();
        buf ^= 1;
    }

#pragma unroll
    for (int k = 0; k < 4; ++k) {
        int r = rg + 32 * k;
        float s = 1.0f / pivarr[r];
        float4* dst = (float4*)(A + (size_t)r * NX);
        float4 v2 = R[k][2];
        v2.x *= s; v2.y *= s; v2.z *= s; v2.w *= s;
        dst[seg] = v2;
        float4 v3 = R[k][3];
        v3.x *= s; v3.y *= s; v3.z *= s; v3.w *= s;
        dst[seg + 16] = v3;
    }
}

/* ---- descriptor tables (device) ---- */
struct MMDesc { const float* X; const float* Y; float* Z; int N; int ldX; int ldY; int ldZ; int Mrows; };
struct MMB { MMDesc d[4]; };

__device__ __forceinline__ MMDesc get_desc(int sd, float* ws, const float* Bm,
                                           const float* Cc) {
    float* A   = ws + OFF_A;
    float* A2  = ws + OFF_E;
    float* A4  = ws + OFF_F;
    float* A8  = ws + OFF_A8;
    float* A16 = ws + OFF_A16;
    float* A32 = ws + OFF_A32;
    float* A64 = ws + OFF_A64;
    float* Dm  = ws + OFF_D;
    float* Pm  = ws + OFF_P;
    float* WF  = ws + OFF_WF;
    MMDesc r = { nullptr, nullptr, nullptr, 0, 0, 0, 0, 0 };
    switch (sd) {
    case 0:  r = { A, A,  A2,          128, NX, NX, NX,  128 }; break;
    case 1:  r = { Cc, A, Dm,          128, NX, NX, NX,  64  }; break;
    case 2:  r = { Cc, Bm, Pm,          64, NX, NU, 64,  64  }; break;
    case 3:  r = { Bm, nullptr, WF + 4032, 64, NU, 0, 4096, 128 }; break;
    case 4:  r = { A2, A2, A4,         128, NX, NX, NX,  128 }; break;
    case 5:  r = { Dm, A,  Dm + 8192,  128, NX, NX, NX,  64  }; break;
    case 6:  r = { Dm, Bm, Pm + 4096,   64, NX, NU, 64,  64  }; break;
    case 7:  r = { A, WF + 4032, WF + 3968, 64, NX, 4096, 4096, 128 }; break;
    case 8:  r = { A4, A4, A8,              128, NX, NX, NX, 128 }; break;
    case 9:  r = { Dm + 8192, A, Dm + 16384, 128, NX, NX, NX, 64 }; break;
    case 10: r = { Dm + 8192, Bm, Pm + 8192,  64, NX, NU, 64, 64 }; break;
    case 11: r = { A2, WF + 3968, WF + 3840, 128, NX, 4096, 4096, 128 }; break;
    case 12: r = { A8, A8, A16,              128, NX, NX, NX, 128 }; break;
    case 13: r = { Dm + 8192, A2, Dm + 24576, 128, NX, NX, NX, 64 }; break;
    case 14: r = { Dm + 16384, Bm, Pm + 12288, 64, NX, NU, 64, 64 }; break;
    case 15: r = { A4, WF + 3840, WF + 3584, 256, NX, 4096, 4096, 128 }; break;
    case 16: r = { A16, A16, A32,             128, NX, NX, NX, 128 }; break;
    case 17: r = { Dm + 16384, A2, Dm + 32768, 128, NX, NX, NX, 64 }; break;
    case 18: r = { Dm + 24576, Bm, Pm + 16384,  64, NX, NU, 64, 64 }; break;
    case 19: r = { A8, WF + 3584, WF + 3072, 512, NX, 4096, 4096, 128 }; break;
    case 20: r = { A32, A32, A64,             128, NX, NX, NX, 128 }; break;
    case 21: r = { Dm + 8192, A4, Dm + 40960,  128, NX, NX, NX, 64 }; break;
    case 22: r = { Dm + 32768, Bm, Pm + 20480,  64, NX, NU, 64, 64 }; break;
    case 23: r = { A16, WF + 3072, WF + 2048, 1024, NX, 4096, 4096, 128 }; break;
    case 24: r = { A32, WF + 2048, WF, 2048, NX, 4096, 4096, 128 }; break;
    case 25: r = { Dm + 16384, A4, Dm + 49152, 128, NX, NX, NX, 64 }; break;
    case 26: r = { Dm + 40960, Bm, Pm + 24576,  64, NX, NU, 64, 64 }; break;
    default: break;
    }
    return r;
}

/* ---- software grid barrier: per-stage counters, device-scope atomics ---- */
__device__ __forceinline__ void gbar(int* bar, int s, int nblk) {
    __syncthreads();
    if (threadIdx.x == 0) {
        __threadfence();
        atomicAdd(&bar[s], 1);
        while (atomicAdd(&bar[s], 0) < nblk) __builtin_amdgcn_s_sleep(2);
        __threadfence();
    }
    __syncthreads();
}

/* ---- K3 (persistent): 7 mmb stages + WT/WF-cvt stage, one launch ----
   CHAIN_NB blocks x 128 thr, 0 LDS -> all co-resident (no deadlock). */
__global__ __launch_bounds__(128) void chainw_kernel(float* ws, const float* Bm,
                                                     const float* Cc, int* bar) {
    unsigned short* WT  = (unsigned short*)(ws + OFF_WT);
    float* WF = ws + OFF_WF;
    unsigned short* WBH = (unsigned short*)(ws + OFF_WBH);
    unsigned short* WBL = (unsigned short*)(ws + OFF_WBL);
    const float* Dm = ws + OFF_D;
    const float* Pm = ws + OFF_P;
    int bid = blockIdx.x;
    const int nblk = gridDim.x;

    for (int s = 0; s < 7; ++s) {
        MMDesc dd[4];
        int pre[5];
        pre[0] = 0;
#pragma unroll
        for (int d = 0; d < 4; ++d) {
            dd[d] = get_desc(s * 4 + d, ws, Bm, Cc);
            int nc = dd[d].Z ? ((dd[d].N + 127) >> 7) : 0;
            pre[d + 1] = pre[d] + (dd[d].Z ? dd[d].Mrows * nc : 0);
        }
        for (int item = bid; item < pre[4]; item += nblk) {
            int d = 0;
            while (item >= pre[d + 1]) ++d;
            int local = item - pre[d];
            int nc = (dd[d].N + 127) >> 7;
            int i = local / nc;
            int jt = local - i * nc;
            int j = jt * 128 + threadIdx.x;
            if (j < dd[d].N) {
                if (dd[d].Y == nullptr) {
                    dd[d].Z[(size_t)i * dd[d].ldZ + j] = dd[d].X[(size_t)i * dd[d].ldX + j];
                } else {
                    const float* xr = dd[d].X + (size_t)i * dd[d].ldX;
                    const float* yc = dd[d].Y + j;
                    float a0 = 0.f, a1 = 0.f, a2 = 0.f, a3 = 0.f;
                    for (int m = 0; m < 128; m += 4) {
                        a0 += xr[m]     * yc[(size_t)(m)     * dd[d].ldY];
                        a1 += xr[m + 1] * yc[(size_t)(m + 1) * dd[d].ldY];
                        a2 += xr[m + 2] * yc[(size_t)(m + 2) * dd[d].ldY];
                        a3 += xr[m + 3] * yc[(size_t)(m + 3) * dd[d].ldY];
                    }
                    dd[d].Z[(size_t)i * dd[d].ldZ + j] = (a0 + a1) + (a2 + a3);
                }
            }
        }
        gbar(bar, s, nblk);
    }
    /* stage 8: WT assemble (512 rows x 5 tiles) + WF hi/lo split */
    const int wtTiles = 512 * 5;
    const int n4 = NX * 4096 / 4;
    const int cvtTiles = (n4 + 127) >> 7;
    for (int item = bid; item < wtTiles + cvtTiles; item += nblk) {
        if (item < wtTiles) {
            int o = item / 5, ft = item - (item / 5) * 5;
            int f = ft * 128 + threadIdx.x;
            if (f < 576) {
                int k = o >> 6, yi = o & 63;
                float v = 0.f;
                if (f < 128) {
                    v = (k == 0) ? Cc[(size_t)yi * NX + f]
                                 : Dm[(size_t)(k - 1) * 64 * NX + (size_t)yi * NX + f];
                } else {
                    int jj = (f - 128) >> 6, e = (f - 128) & 63;
                    if (k > jj) v = Pm[(size_t)(k - 1 - jj) * 64 * 64 + (size_t)yi * 64 + e];
                }
                WT[(size_t)o * 576 + f] = f2bf(v);
            }
        } else {
            size_t idx = (size_t)(item - wtTiles) * 128 + threadIdx.x;
            if (idx < (size_t)n4) cvt_one(WF, WBH, WBL, idx);
        }
    }
}

/* ---- mmb (fallback path only), column-tiled ---- */
__global__ __launch_bounds__(128) void mmb_kernel(MMB mm) {
    MMDesc d = mm.d[blockIdx.y];
    if (d.Z == nullptr) return;
    int nct = (d.N + 127) >> 7;
    int i = blockIdx.x / nct;
    int jt = blockIdx.x - i * nct;
    if (i >= d.Mrows) return;
    int j = jt * 128 + threadIdx.x;
    if (j >= d.N) return;
    if (d.Y == nullptr) {
        d.Z[(size_t)i * d.ldZ + j] = d.X[(size_t)i * d.ldX + j];
        return;
    }
    const float* xr = d.X + (size_t)i * d.ldX;
    float a0 = 0.f, a1 = 0.f, a2 = 0.f, a3 = 0.f;
    for (int m = 0; m < 128; m += 4) {
        a0 += xr[m]     * d.Y[(size_t)(m)     * d.ldY + j];
        a1 += xr[m + 1] * d.Y[(size_t)(m + 1) * d.ldY + j];
        a2 += xr[m + 2] * d.Y[(size_t)(m + 2) * d.ldY + j];
        a3 += xr[m + 3] * d.Y[(size_t)(m + 3) * d.ldY + j];
    }
    d.Z[(size_t)i * d.ldZ + j] = (a0 + a1) + (a2 + a3);
}

/* ---- K4 (fused): blocks 0..255 L-GEMM K-split x8; 256..511 v8-GEMM ---- */
__global__ __launch_bounds__(256) void lvgemm_kernel(const unsigned short* __restrict__ UH,
                                                     const unsigned short* __restrict__ UL,
                                                     const unsigned short* __restrict__ WH,
                                                     const unsigned short* __restrict__ WL,
                                                     float* __restrict__ Lp,
                                                     float* __restrict__ V8) {
    int t = threadIdx.x;
    int w = t >> 6, l = t & 63;
    int l16 = l & 15, l4 = l >> 4;
    int o0 = w * 32 + l16;
    f32x4 acc[4][2];
#pragma unroll
    for (int mt = 0; mt < 4; ++mt)
#pragma unroll
        for (int nt = 0; nt < 2; ++nt) acc[mt][nt] = (f32x4){0.f, 0.f, 0.f, 0.f};

    if (blockIdx.x < 256) {
        int blk = blockIdx.x & 31;
        int kblk = blockIdx.x >> 5;
        size_t uoff[4];
#pragma unroll
        for (int mt = 0; mt < 4; ++mt) {
            int pair = blk * 64 + mt * 16 + l16;
            int b = pair & 31, c = pair >> 5;
            uoff[mt] = ((size_t)b * T_LEN + (size_t)c * KCH) * NU;
        }
        int kt0 = kblk * (128 / KSPLIT);
        for (int kt = kt0; kt < kt0 + 128 / KSPLIT; ++kt) {
            int feat = kt * 32 + l4 * 8;
            bf16x8 ah[4], al[4], bh[2], bl[2];
#pragma unroll
            for (int mt = 0; mt < 4; ++mt) {
                ah[mt] = *(const bf16x8*)(UH + uoff[mt] + feat);
                al[mt] = *(const bf16x8*)(UL + uoff[mt] + feat);
            }
#pragma unroll
            for (int nt = 0; nt < 2; ++nt) {
                size_t woff = (size_t)(o0 + nt * 16) * 4096 + feat;
                bh[nt] = *(const bf16x8*)(WH + woff);
                bl[nt] = *(const bf16x8*)(WL + woff);
            }
#pragma unroll
            for (int mt = 0; mt < 4; ++mt)
#pragma unroll
                for (int nt = 0; nt < 2; ++nt) {
                    acc[mt][nt] = __builtin_amdgcn_mfma_f32_16x16x32_bf16(
                        ah[mt], bh[nt], acc[mt][nt], 0, 0, 0);
                    acc[mt][nt] = __builtin_amdgcn_mfma_f32_16x16x32_bf16(
                        ah[mt], bl[nt], acc[mt][nt], 0, 0, 0);
                    acc[mt][nt] = __builtin_amdgcn_mfma_f32_16x16x32_bf16(
                        al[mt], bh[nt], acc[mt][nt], 0, 0, 0);
                }
        }
        float* lout = Lp + (size_t)kblk * 2048 * NX;
#pragma unroll
        for (int mt = 0; mt < 4; ++mt)
#pragma unroll
            for (int nt = 0; nt < 2; ++nt)
#pragma unroll
                for (int reg = 0; reg < 4; ++reg) {
                    int r = blk * 64 + mt * 16 + l4 * 4 + reg;
                    lout[(size_t)r * NX + o0 + nt * 16] = acc[mt][nt][reg];
                }
    } else {
        int blk = blockIdx.x - 256;
        size_t uoff[4];
#pragma unroll
        for (int mt = 0; mt < 4; ++mt) {
            int r = blk * 64 + mt * 16 + l16;
            int pair = r >> 3, q = r & 7;
            int b = pair & 31, c = pair >> 5;
            uoff[mt] = ((size_t)b * T_LEN + (size_t)c * KCH + (size_t)q * 8) * NU;
        }
#pragma unroll 2
        for (int kt = 0; kt < 16; ++kt) {
            int feat = kt * 32 + l4 * 8;
            bf16x8 ah[4], al[4], bh[2], bl[2];
#pragma unroll
            for (int mt = 0; mt < 4; ++mt) {
                ah[mt] = *(const bf16x8*)(UH + uoff[mt] + feat);
                al[mt] = *(const bf16x8*)(UL + uoff[mt] + feat);
            }
#pragma unroll
            for (int nt = 0; nt < 2; ++nt) {
                size_t woff = (size_t)(o0 + nt * 16) * 4096 + 3584 + feat;
                bh[nt] = *(const bf16x8*)(WH + woff);
                bl[nt] = *(const bf16x8*)(WL + woff);
            }
#pragma unroll
            for (int mt = 0; mt < 4; ++mt)
#pragma unroll
                for (int nt = 0; nt < 2; ++nt) {
                    acc[mt][nt] = __builtin_amdgcn_mfma_f32_16x16x32_bf16(
                        ah[mt], bh[nt], acc[mt][nt], 0, 0, 0);
                    acc[mt][nt] = __builtin_amdgcn_mfma_f32_16x16x32_bf16(
                        ah[mt], bl[nt], acc[mt][nt], 0, 0, 0);
                    acc[mt][nt] = __builtin_amdgcn_mfma_f32_16x16x32_bf16(
                        al[mt], bh[nt], acc[mt][nt], 0, 0, 0);
                }
        }
#pragma unroll
        for (int mt = 0; mt < 4; ++mt)
#pragma unroll
            for (int nt = 0; nt < 2; ++nt)
#pragma unroll
                for (int reg = 0; reg < 4; ++reg) {
                    int r = blk * 64 + mt * 16 + l4 * 4 + reg;
                    V8[(size_t)r * NX + o0 + nt * 16] = acc[mt][nt][reg];
                }
    }
}

/* ---- K5: phase 2 with inline Lp reduce ---- */
__global__ __launch_bounds__(128) void phase2_kernel(const float* __restrict__ AK,
                                                     const float* __restrict__ Lp,
                                                     const float* __restrict__ x0,
                                                     float* __restrict__ Xc) {
    __shared__ float Ks[NX][NX + 1];
    __shared__ float xs[NX];
    int tid = threadIdx.x, b = blockIdx.x;
    for (int idx = tid; idx < NX * NX; idx += 128)
        Ks[idx >> 7][idx & 127] = AK[idx];
    float x = x0[tid];
    xs[tid] = x;
    Xc[(size_t)(0 * BATCH + b) * NX + tid] = x;
    __syncthreads();
    for (int c = 0; c < NC - 1; ++c) {
        size_t lidx = ((size_t)c * BATCH + b) * NX + tid;
        float lsum = 0.f;
#pragma unroll
        for (int k = 0; k < KSPLIT; ++k) lsum += Lp[(size_t)k * 2048 * NX + lidx];
        float a0 = 0.f, a1 = 0.f, a2 = 0.f, a3 = 0.f;
        for (int j = 0; j < NX; j += 4) {
            a0 += Ks[tid][j]     * xs[j];
            a1 += Ks[tid][j + 1] * xs[j + 1];
            a2 += Ks[tid][j + 2] * xs[j + 2];
            a3 += Ks[tid][j + 3] * xs[j + 3];
        }
        float xn = (a0 + a1) + (a2 + a3) + lsum;
        __syncthreads();
        xs[tid] = xn;
        Xc[((size_t)(c + 1) * BATCH + b) * NX + tid] = xn;
        __syncthreads();
    }
}

/* ---- fallback phase2 (reads plain L) ---- */
__global__ __launch_bounds__(128) void phase2fb_kernel(const float* __restrict__ AK,
                                                       const float* __restrict__ L,
                                                       const float* __restrict__ x0,
                                                       float* __restrict__ Xc) {
    __shared__ float Ks[NX][NX + 1];
    __shared__ float xs[NX];
    int tid = threadIdx.x, b = blockIdx.x;
    for (int idx = tid; idx < NX * NX; idx += 128)
        Ks[idx >> 7][idx & 127] = AK[idx];
    float x = x0[tid];
    xs[tid] = x;
    Xc[(size_t)(0 * BATCH + b) * NX + tid] = x;
    __syncthreads();
    for (int c = 0; c < NC - 1; ++c) {
        float a0 = 0.f, a1 = 0.f, a2 = 0.f, a3 = 0.f;
        for (int j = 0; j < NX; j += 4) {
            a0 += Ks[tid][j]     * xs[j];
            a1 += Ks[tid][j + 1] * xs[j + 1];
            a2 += Ks[tid][j + 2] * xs[j + 2];
            a3 += Ks[tid][j + 3] * xs[j + 3];
        }
        float xn = (a0 + a1) + (a2 + a3) + L[((size_t)c * BATCH + b) * NX + tid];
        __syncthreads();
        xs[tid] = xn;
        Xc[((size_t)(c + 1) * BATCH + b) * NX + tid] = xn;
        __syncthreads();
    }
}

/* ---- K6: chain8 — z <- A8 z + v8[q], 8 iters; emits x_{8q} bf16 ---- */
__global__ __launch_bounds__(256, 4) void chain8_kernel(const float* __restrict__ A8,
                                                        const float* __restrict__ V8,
                                                        const float* __restrict__ Xc,
                                                        unsigned short* __restrict__ X8) {
    int t = threadIdx.x;
    int g = t >> 3, seg = t & 7;
    int pair = blockIdx.x;

    float4 A8r[4][4];
#pragma unroll
    for (int r = 0; r < 4; ++r) {
        const float4* ap = (const float4*)(A8 + (size_t)(g + 32 * r) * NX + seg * 16);
        A8r[r][0] = ap[0]; A8r[r][1] = ap[1]; A8r[r][2] = ap[2]; A8r[r][3] = ap[3];
    }

    __shared__ __align__(16) float xs[2][192];
    __shared__ float vs[2][128];
    float vreg = 0.f;
    if (t < NX) {
        xs[0][XP(t)] = Xc[(size_t)pair * NX + t];
        vreg = V8[((size_t)pair * 8) * NX + t];
    }

    int buf = 0;
    for (int m = 0; m < 8; ++m) {
        if (t < NX) vs[buf][t] = vreg;
        if (t < NX && m < 7) vreg = V8[((size_t)pair * 8 + m + 1) * NX + t];
        __syncthreads();
        if (t < NX) X8[((size_t)pair * 8 + m) * NX + t] = f2bf(xs[buf][XP(t)]);
        const float4* xq0 = (const float4*)&xs[buf][seg * 24];
        const float4* xq1 = (const float4*)&xs[buf][seg * 24 + 12];
        float4 x0 = xq0[0], x1 = xq0[1], x2 = xq1[0], x3 = xq1[1];
        float acc[4];
#pragma unroll
        for (int r = 0; r < 4; ++r) {
            acc[r] = (f4dot(A8r[r][0], x0) + f4dot(A8r[r][1], x1))
                   + (f4dot(A8r[r][2], x2) + f4dot(A8r[r][3], x3));
        }
#pragma unroll
        for (int d = 1; d <= 4; d <<= 1) {
#pragma unroll
            for (int r = 0; r < 4; ++r) acc[r] += __shfl_xor(acc[r], d);
        }
        if (seg == 0) {
            xs[buf ^ 1][XP(g)]      = acc[0] + vs[buf][g];
            xs[buf ^ 1][XP(g + 32)] = acc[1] + vs[buf][g + 32];
            xs[buf ^ 1][XP(g + 64)] = acc[2] + vs[buf][g + 64];
            xs[buf ^ 1][XP(g + 96)] = acc[3] + vs[buf][g + 96];
        }
        buf ^= 1;
    }
}

/* ---- K7: MFMA y-emit (stride 8) ---- */
__global__ __launch_bounds__(512) void yemit_mfma_kernel(const unsigned short* __restrict__ X8,
                                                         const unsigned short* __restrict__ ub,
                                                         const unsigned short* __restrict__ WT,
                                                         float* __restrict__ y) {
    int t = threadIdx.x;
    int w = t >> 6, l = t & 63;
    int l16 = l & 15, l4 = l >> 4;
    int blk = blockIdx.x;
    f32x4 acc[4][4];
#pragma unroll
    for (int mt = 0; mt < 4; ++mt)
#pragma unroll
        for (int nt = 0; nt < 4; ++nt) acc[mt][nt] = (f32x4){0.f, 0.f, 0.f, 0.f};
    int grow[4];
    const unsigned short* ubase[4];
#pragma unroll
    for (int mt = 0; mt < 4; ++mt) {
        grow[mt] = blk * 64 + mt * 16 + l16;
        int pair = grow[mt] >> 3, q = grow[mt] & 7;
        int b = pair & 31, cc = pair >> 5;
        ubase[mt] = ub + ((size_t)b * T_LEN + (size_t)cc * KCH + (size_t)q * 8) * NU;
    }
#pragma unroll 2
    for (int kt = 0; kt < 18; ++kt) {
        int feat = kt * 32 + l4 * 8;
        bf16x8 afr[4];
#pragma unroll
        for (int mt = 0; mt < 4; ++mt) {
            const unsigned short* ap;
            if (feat < 128) ap = X8 + (size_t)grow[mt] * NX + feat;
            else            ap = ubase[mt] + (feat - 128);
            afr[mt] = *(const bf16x8*)ap;
        }
        bf16x8 bfr[4];
#pragma unroll
        for (int nt = 0; nt < 4; ++nt) {
            int o = w * 64 + nt * 16 + l16;
            bfr[nt] = *(const bf16x8*)(WT + (size_t)o * 576 + feat);
        }
#pragma unroll
        for (int mt = 0; mt < 4; ++mt)
#pragma unroll
            for (int nt = 0; nt < 4; ++nt)
                acc[mt][nt] = __builtin_amdgcn_mfma_f32_16x16x32_bf16(
                    afr[mt], bfr[nt], acc[mt][nt], 0, 0, 0);
    }
#pragma unroll
    for (int mt = 0; mt < 4; ++mt) {
#pragma unroll
        for (int nt = 0; nt < 4; ++nt) {
            int o = w * 64 + nt * 16 + l16;
            int k = o >> 6, yi = o & 63;
#pragma unroll
            for (int reg = 0; reg < 4; ++reg) {
                int r = blk * 64 + mt * 16 + l4 * 4 + reg;
                int pair = r >> 3, q = r & 7;
                int b = pair & 31, cc = pair >> 5;
                int tt = cc * KCH + q * 8 + k;
                y[((size_t)b * T_LEN + tt) * NY + yi] = acc[mt][nt][reg];
            }
        }
    }
}

/* ---- fallback path kernels (ws too small) ---- */
__global__ __launch_bounds__(512, 4) void phase1_kernel(const float* __restrict__ u_,
                                                        const float* __restrict__ A4,
                                                        const float* __restrict__ G,
                                                        float* __restrict__ L) {
    int t = threadIdx.x;
    int g = t >> 4, seg = t & 15;
    int pair = blockIdx.x;
    int c = pair >> 5, b = pair & 31;
    const float* urow = u_ + ((size_t)b * T_LEN + (size_t)c * KCH) * NU;
    float4 A4r[4][2], Gr[4][4];
#pragma unroll
    for (int r = 0; r < 4; ++r) {
        const float4* ap = (const float4*)(A4 + (size_t)(g + 32 * r) * NX + seg * 8);
        A4r[r][0] = ap[0]; A4r[r][1] = ap[1];
        const float4* gp = (const float4*)(G + (size_t)(g + 32 * r) * 256 + seg * 16);
        Gr[r][0] = gp[0]; Gr[r][1] = gp[1]; Gr[r][2] = gp[2]; Gr[r][3] = gp[3];
    }
    __shared__ __align__(16) float xs[2][192];
    __shared__ __align__(16) float us[2][320];
    if (t < NX) xs[0][XP(t)] = 0.f;
    float up = (t < 256) ? urow[t] : 0.f;
    int buf = 0;
    for (int m = 0; m < 16; ++m) {
        if (t < 256) us[buf][UP16(t)] = up;
        if (t < 256 && m < 15) up = urow[(size_t)(m + 1) * 256 + t];
        __syncthreads();
        const float4* xq = (const float4*)&xs[buf][seg * 12];
        float4 xa = xq[0], xb = xq[1];
        const float4* uq = (const float4*)&us[buf][seg * 20];
        float acc0[4], acc1[4];
#pragma unroll
        for (int r = 0; r < 4; ++r) {
            acc0[r] = f4dot(A4r[r][0], xa);
            acc1[r] = f4dot(A4r[r][1], xb);
        }
#pragma unroll
        for (int q = 0; q < 4; ++q) {
            float4 uv = uq[q];
#pragma unroll
            for (int r = 0; r < 4; ++r) {
                float pr = f4dot(Gr[r][q], uv);
                if (q & 1) acc1[r] += pr; else acc0[r] += pr;
            }
        }
        float acc[4];
#pragma unroll
        for (int r = 0; r < 4; ++r) acc[r] = acc0[r] + acc1[r];
#pragma unroll
        for (int d = 1; d <= 8; d <<= 1) {
#pragma unroll
            for (int r = 0; r < 4; ++r) acc[r] += __shfl_xor(acc[r], d);
        }
        if (seg == 0) {
            xs[buf ^ 1][XP(g)]      = acc[0];
            xs[buf ^ 1][XP(g + 32)] = acc[1];
            xs[buf ^ 1][XP(g + 64)] = acc[2];
            xs[buf ^ 1][XP(g + 96)] = acc[3];
        }
        buf ^= 1;
    }
    __syncthreads();
    if (t < NX) L[(size_t)pair * NX + t] = xs[buf][XP(t)];
}

__global__ __launch_bounds__(256) void phase3_fb_kernel(const float* __restrict__ u_,
                                                        const float* __restrict__ A,
                                                        const float* __restrict__ Bm,
                                                        const float* __restrict__ C,
                                                        const float* __restrict__ Xc,
                                                        float* __restrict__ y) {
    int t = threadIdx.x;
    int i = t >> 1, h = t & 1;
    int r = t >> 2, q = t & 3;
    int pair = blockIdx.x;
    int c = pair >> 5, b = pair & 31;
    const float* urow = u_ + ((size_t)b * T_LEN + (size_t)c * KCH) * NU;
    float* yrow = y + ((size_t)b * T_LEN + (size_t)c * KCH) * NY;
    float Ar[64];
    {
        const float4* Arow = (const float4*)(A + (size_t)i * NX + h * 64);
#pragma unroll
        for (int j4 = 0; j4 < 16; ++j4) {
            float4 v = Arow[j4];
            Ar[4 * j4] = v.x; Ar[4 * j4 + 1] = v.y; Ar[4 * j4 + 2] = v.z; Ar[4 * j4 + 3] = v.w;
        }
    }
    float Br[32];
    {
        const float4* Brow = (const float4*)(Bm + (size_t)i * NU + h * 32);
#pragma unroll
        for (int j4 = 0; j4 < 8; ++j4) {
            float4 v = Brow[j4];
            Br[4 * j4] = v.x; Br[4 * j4 + 1] = v.y; Br[4 * j4 + 2] = v.z; Br[4 * j4 + 3] = v.w;
        }
    }
    float Cr[32];
    {
        const float4* Crow = (const float4*)(C + (size_t)r * NX + q * 32);
#pragma unroll
        for (int j4 = 0; j4 < 8; ++j4) {
            float4 v = Crow[j4];
            Cr[4 * j4] = v.x; Cr[4 * j4 + 1] = v.y; Cr[4 * j4 + 2] = v.z; Cr[4 * j4 + 3] = v.w;
        }
    }
    __shared__ float xs[2][NX];
    __shared__ float us[2][NU];
    if (h == 0) xs[0][i] = Xc[(size_t)pair * NX + i];
    float up = (t < NU) ? urow[t] : 0.f;
    __syncthreads();
    {
        float c0 = 0.f, c1 = 0.f, c2 = 0.f, c3 = 0.f;
        const float* xp = &xs[0][q * 32];
#pragma unroll
        for (int j = 0; j < 32; j += 4) {
            c0 += Cr[j]     * xp[j];
            c1 += Cr[j + 1] * xp[j + 1];
            c2 += Cr[j + 2] * xp[j + 2];
            c3 += Cr[j + 3] * xp[j + 3];
        }
        float s = (c0 + c1) + (c2 + c3);
        s += __shfl_xor(s, 1);
        s += __shfl_xor(s, 2);
        if (q == 0) yrow[r] = s;
    }
    int buf = 0;
    for (int k = 1; k < KCH; ++k) {
        if (t < NU) us[buf][t] = up;
        if (k < KCH - 1 && t < NU) up = urow[(size_t)k * NU + t];
        __syncthreads();
        float a0 = 0.f, a1 = 0.f, a2 = 0.f, a3 = 0.f;
        const float* xp = &xs[buf][h * 64];
        const float* upp = &us[buf][h * 32];
#pragma unroll
        for (int j = 0; j < 64; j += 4) {
            a0 += Ar[j]     * xp[j];
            a1 += Ar[j + 1] * xp[j + 1];
            a2 += Ar[j + 2] * xp[j + 2];
            a3 += Ar[j + 3] * xp[j + 3];
        }
#pragma unroll
        for (int j = 0; j < 32; j += 4) {
            a0 += Br[j]     * upp[j];
            a1 += Br[j + 1] * upp[j + 1];
            a2 += Br[j + 2] * upp[j + 2];
            a3 += Br[j + 3] * upp[j + 3];
        }
        float a = (a0 + a1) + (a2 + a3);
        float s = a + __shfl_xor(a, 1);
        if (h == 0) xs[buf ^ 1][i] = s;
        __syncthreads();
        float c0 = 0.f, c1 = 0.f, c2 = 0.f, c3 = 0.f;
        const float* xcp = &xs[buf ^ 1][q * 32];
#pragma unroll
        for (int j = 0; j < 32; j += 4) {
            c0 += Cr[j]     * xcp[j];
            c1 += Cr[j + 1] * xcp[j + 1];
            c2 += Cr[j + 2] * xcp[j + 2];
            c3 += Cr[j + 3] * xcp[j + 3];
        }
        float sy = (c0 + c1) + (c2 + c3);
        sy += __shfl_xor(sy, 1);
        sy += __shfl_xor(sy, 2);
        if (q == 0) yrow[(size_t)k * NY + r] = sy;
        buf ^= 1;
    }
}

extern "C" void kernel_launch(void* const* d_in, const int* in_sizes, int n_in,
                              void* d_out, int out_size, void* d_ws, size_t ws_size,
                              hipStream_t stream) {
    const float* u_  = (const float*)d_in[0];
    const float* M   = (const float*)d_in[1];
    const float* Bm  = (const float*)d_in[2];
    const float* C   = (const float*)d_in[3];
    const float* x0  = (const float*)d_in[4];
    float* y = (float*)d_out;
    float* ws = (float*)d_ws;

    float* E   = ws + OFF_E;
    float* F   = ws + OFF_F;
    float* A   = ws + OFF_A;
    float* A2  = ws + OFF_E;
    float* A4  = ws + OFF_F;
    float* G   = ws + OFF_G;
    float* A8  = ws + OFF_A8;
    float* A16 = ws + OFF_A16;
    float* A32 = ws + OFF_A32;
    float* A64 = ws + OFF_A64;
    unsigned short* WT  = (unsigned short*)(ws + OFF_WT);
    unsigned short* WBH = (unsigned short*)(ws + OFF_WBH);
    unsigned short* WBL = (unsigned short*)(ws + OFF_WBL);
    float* Xc  = ws + OFF_XC;
    float* L   = ws + OFF_L;
    int*   bar = (int*)(ws + OFF_L);   /* fast path: barrier counters */
    float* V8  = ws + OFF_V8;
    unsigned short* X8  = (unsigned short*)(ws + OFF_X8);
    unsigned short* UBH = (unsigned short*)(ws + OFF_UBH);
    unsigned short* UBL = (unsigned short*)(ws + OFF_UBL);
    float* Lp  = ws + OFF_LP;

    bool fast = ws_size >= (size_t)WS_NEED_FLOATS * sizeof(float);
    int n4 = BATCH * T_LEN * NU / 4;

    ef_kernel<<<256, 128, 0, stream>>>(M, E, F);

    if (fast) {
        hipMemsetAsync(bar, 0, 32, stream);
        solvecvt_kernel<<<257, 512, 0, stream>>>(E, F, A, u_, UBH, UBL, n4);
        chainw_kernel<<<CHAIN_NB, 128, 0, stream>>>(ws, Bm, C, bar);
        lvgemm_kernel<<<512, 256, 0, stream>>>(UBH, UBL, WBH, WBL, Lp, V8);
        phase2_kernel<<<BATCH, 128, 0, stream>>>(A64, Lp, x0, Xc);
        chain8_kernel<<<NC * BATCH, 256, 0, stream>>>(A8, V8, Xc, X8);
        yemit_mfma_kernel<<<256, 512, 0, stream>>>(X8, UBH, WT, y);
    } else {
        solvecvt_kernel<<<1, 512, 0, stream>>>(E, F, A, u_, nullptr, nullptr, n4);
        { MMB mm;
          mm.d[0] = { A, A,  A2,       128, NX, NX, NX,  128 };
          mm.d[1] = { A, Bm, G + 128,   64, NX, NU, 256, 128 };
          mm.d[2] = { Bm, nullptr, G + 192, 64, NU, 0, 256, 128 };
          mm.d[3] = { nullptr, nullptr, nullptr, 0, 0, 0, 0, 0 };
          mmb_kernel<<<dim3(128, 4), 128, 0, stream>>>(mm); }
        { MMB mm;
          mm.d[0] = { A2, A2, A4,   128, NX, NX,  NX,  128 };
          mm.d[1] = { A2, G + 128, G, 128, NX, 256, 256, 128 };
          mm.d[2] = { nullptr, nullptr, nullptr, 0, 0, 0, 0, 0 };
          mm.d[3] = { nullptr, nullptr, nullptr, 0, 0, 0, 0, 0 };
          mmb_kernel<<<dim3(256, 4), 128, 0, stream>>>(mm); }
        { MMB mm;
          mm.d[0] = { A4, A4, A8,    128, NX, NX, NX, 128 };
          mm.d[1] = { nullptr, nullptr, nullptr, 0, 0, 0, 0, 0 };
          mm.d[2] = { nullptr, nullptr, nullptr, 0, 0, 0, 0, 0 };
          mm.d[3] = { nullptr, nullptr, nullptr, 0, 0, 0, 0, 0 };
          mmb_kernel<<<dim3(128, 4), 128, 0, stream>>>(mm); }
        { MMB mm;
          mm.d[0] = { A8, A8, A16,   128, NX, NX, NX, 128 };
          mm.d[1] = { nullptr, nullptr, nullptr, 0, 0, 0, 0, 0 };
          mm.d[2] = { nullptr, nullptr, nullptr, 0, 0, 0, 0, 0 };
          mm.d[3] = { nullptr, nullptr, nullptr, 0, 0, 0, 0, 0 };
          mmb_kernel<<<dim3(128, 4), 128, 0, stream>>>(mm); }
        { MMB mm;
          mm.d[0] = { A16, A16, A32, 128, NX, NX, NX, 128 };
          mm.d[1] = { nullptr, nullptr, nullptr, 0, 0, 0, 0, 0 };
          mm.d[2] = { nullptr, nullptr, nullptr, 0, 0, 0, 0, 0 };
          mm.d[3] = { nullptr, nullptr, nullptr, 0, 0, 0, 0, 0 };
          mmb_kernel<<<dim3(128, 4), 128, 0, stream>>>(mm); }
        { MMB mm;
          mm.d[0] = { A32, A32, A64, 128, NX, NX, NX, 128 };
          mm.d[1] = { nullptr, nullptr, nullptr, 0, 0, 0, 0, 0 };
          mm.d[2] = { nullptr, nullptr, nullptr, 0, 0, 0, 0, 0 };
          mm.d[3] = { nullptr, nullptr, nullptr, 0, 0, 0, 0, 0 };
          mmb_kernel<<<dim3(128, 4), 128, 0, stream>>>(mm); }
        phase1_kernel<<<NC * BATCH, 512, 0, stream>>>(u_, A4, G, L);
        phase2fb_kernel<<<BATCH, 128, 0, stream>>>(A64, L, x0, Xc);
        phase3_fb_kernel<<<NC * BATCH, 256, 0, stream>>>(u_, A, Bm, C, Xc, y);
    }
}

// Round 21
// 285.127 us; speedup vs baseline: 2.4603x; 2.4603x over previous
//
#include <hip/hip_runtime.h>

#define BATCH 32
#define T_LEN 4096
#define NU 64
#define NX 128
#define NY 64
#define KCH 64
#define NC (T_LEN / KCH)
#define KSPLIT 8

/* workspace float offsets */
#define OFF_E    0            /* becomes A2 */
#define OFF_F    16384        /* becomes A4 */
#define OFF_A    32768
#define OFF_G    49152        /* fallback only */
#define OFF_A8   81920
#define OFF_A16  98304
#define OFF_A32  114688
#define OFF_A64  131072
#define OFF_D    147456       /* D1..D7: 7x64x128 */
#define OFF_P    204800       /* P0..P6: 7x64x64 */
#define OFF_WT   233472       /* 512x576 bf16 */
#define OFF_WF   380928       /* [128][4096] f32 */
#define OFF_WBH  905216
#define OFF_WBL  1167360
#define OFF_XC   1429504
#define OFF_L    1691648
#define OFF_V8   1953792
#define OFF_X8   4050944
#define OFF_UBH  5099520
#define OFF_UBL  9293824
#define OFF_LP   13488128
#define WS_NEED_FLOATS (13488128 + 2097152)

__device__ __forceinline__ int XP(int l)   { return l + ((l >> 3) << 2); }
__device__ __forceinline__ int UP16(int l) { return l + ((l >> 4) << 2); }

__device__ __forceinline__ unsigned short f2bf(float f) {
    unsigned int x = __float_as_uint(f);
    unsigned int r = (x + 0x7FFFu + ((x >> 16) & 1u)) >> 16;
    return (unsigned short)r;
}
__device__ __forceinline__ float bf2f(unsigned short h) {
    return __uint_as_float(((unsigned int)h) << 16);
}
__device__ __forceinline__ float4 f4ms(float4 a, float s, float4 b) {
    float4 r;
    r.x = a.x - s * b.x; r.y = a.y - s * b.y;
    r.z = a.z - s * b.z; r.w = a.w - s * b.w;
    return r;
}
__device__ __forceinline__ float f4dot(float4 a, float4 b) {
    return a.x * b.x + a.y * b.y + a.z * b.z + a.w * b.w;
}
__device__ __forceinline__ void cvt_one(const float* __restrict__ src,
                                        unsigned short* __restrict__ hi,
                                        unsigned short* __restrict__ lo,
                                        size_t idx) {
    float4 v = ((const float4*)src)[idx];
    unsigned short h0 = f2bf(v.x), h1 = f2bf(v.y), h2 = f2bf(v.z), h3 = f2bf(v.w);
    unsigned short l0 = f2bf(v.x - bf2f(h0));
    unsigned short l1 = f2bf(v.y - bf2f(h1));
    unsigned short l2 = f2bf(v.z - bf2f(h2));
    unsigned short l3 = f2bf(v.w - bf2f(h3));
    unsigned long long ph = (unsigned long long)h0 | ((unsigned long long)h1 << 16)
                          | ((unsigned long long)h2 << 32) | ((unsigned long long)h3 << 48);
    unsigned long long pl = (unsigned long long)l0 | ((unsigned long long)l1 << 16)
                          | ((unsigned long long)l2 << 32) | ((unsigned long long)l3 << 48);
    ((unsigned long long*)hi)[idx] = ph;
    ((unsigned long long*)lo)[idx] = pl;
}

typedef __attribute__((ext_vector_type(8))) short bf16x8;
typedef __attribute__((ext_vector_type(4))) float f32x4;

/* ---- K1: E/F build ---- */
__global__ __launch_bounds__(128) void ef_kernel(const float* __restrict__ M,
                                                 float* __restrict__ E,
                                                 float* __restrict__ F) {
    int part = blockIdx.x >> 7;
    int i = blockIdx.x & 127;
    int j = threadIdx.x;
    const float* Mi2 = M + (size_t)(128 + i) * 256;
    const float* Mj1 = M + (size_t)j * 256;
    if (part == 0) {
        const float* Mi1 = M + (size_t)i * 256;
        const float* Mj2 = M + (size_t)(128 + j) * 256;
        float s11 = 0.f, s22 = 0.f;
        for (int m = 0; m < 256; ++m) {
            s11 += Mi1[m] * Mj1[m];
            s22 += Mi2[m] * Mj2[m];
        }
        float e = 0.5f * (s11 + s22);
        if (i == j) e += 1e-9f;
        E[i * NX + j] = e;
    } else {
        float s21 = 0.f;
        for (int m = 0; m < 256; ++m) s21 += Mi2[m] * Mj1[m];
        F[i * NX + j] = s21;
    }
}

/* ---- K2 (fused): block 0 = R18-verified solve; blocks >=1 = u hi/lo split ----
   solve occupies 1 CU for ~56us; cvt blocks run concurrently on other CUs. */
__global__ __launch_bounds__(512, 1) void solvecvt_kernel(const float* __restrict__ E,
                                                          const float* __restrict__ F,
                                                          float* __restrict__ A,
                                                          const float* __restrict__ u,
                                                          unsigned short* __restrict__ hi,
                                                          unsigned short* __restrict__ lo,
                                                          int n4) {
    if (blockIdx.x != 0) {
        if (hi == nullptr) return;
        size_t stride = (size_t)(gridDim.x - 1) * 512;
        for (size_t idx = (size_t)(blockIdx.x - 1) * 512 + threadIdx.x; idx < (size_t)n4;
             idx += stride)
            cvt_one(u, hi, lo, idx);
        return;
    }
    __shared__ __align__(16) float praw[2][4][264];
    __shared__ __align__(16) float4 mrowS[2][128];
    __shared__ float pivarr[128];
    int t = threadIdx.x;
    int rg = t >> 4, seg = t & 15;

    float4 R[4][4];
#pragma unroll
    for (int k = 0; k < 4; ++k) {
        int r = rg + 32 * k;
        const float4* erow = (const float4*)(E + (size_t)r * NX);
        const float4* frow = (const float4*)(F + (size_t)r * NX);
        R[k][0] = erow[seg];
        R[k][1] = erow[seg + 16];
        R[k][2] = frow[seg];
        R[k][3] = frow[seg + 16];
    }
    if (rg < 4) {
        float4* dst = (float4*)&praw[0][rg][0];
        dst[seg]      = R[0][0];
        dst[seg + 16] = R[0][1];
        dst[seg + 32] = R[0][2];
        dst[seg + 48] = R[0][3];
    }
    if (seg == 0) {
#pragma unroll
        for (int k = 0; k < 4; ++k) mrowS[0][rg + 32 * k] = R[k][0];
    }
    __syncthreads();

    int buf = 0;
    for (int wd = 0; wd < 32; ++wd) {
        int k0 = 4 * wd;
        const float* p0s = &praw[buf][0][0];
        const float* p1s = &praw[buf][1][0];
        const float* p2s = &praw[buf][2][0];
        const float* p3s = &praw[buf][3][0];
        float p00 = p0s[k0], p01 = p0s[k0 + 1], p02 = p0s[k0 + 2], p03 = p0s[k0 + 3];
        float r10 = p1s[k0], r11 = p1s[k0 + 1], r12 = p1s[k0 + 2], r13 = p1s[k0 + 3];
        float r20 = p2s[k0], r21 = p2s[k0 + 1], r22 = p2s[k0 + 2], r23 = p2s[k0 + 3];
        float r30 = p3s[k0], r31 = p3s[k0 + 1], r32 = p3s[k0 + 2], r33 = p3s[k0 + 3];
        float inv0 = 1.0f / p00;
        float m1 = r10 * inv0;
        float piv1 = r11 - m1 * p01;
        float inv1 = 1.0f / piv1;
        float p12 = r12 - m1 * p02, p13 = r13 - m1 * p03;
        float m2 = r20 * inv0;
        float m2b = (r21 - m2 * p01) * inv1;
        float piv2 = r22 - m2 * p02 - m2b * p12;
        float inv2 = 1.0f / piv2;
        float p23 = r23 - m2 * p03 - m2b * p13;
        float m3 = r30 * inv0;
        float m3b = (r31 - m3 * p01) * inv1;
        float m3c = (r32 - m3 * p02 - m3b * p12) * inv2;
        float piv3 = r33 - m3 * p03 - m3b * p13 - m3c * p23;
        float inv3 = 1.0f / piv3;
        if (t == 0) {
            pivarr[k0] = p00; pivarr[k0 + 1] = piv1;
            pivarr[k0 + 2] = piv2; pivarr[k0 + 3] = piv3;
        }
        float q0[4], q1[4], q2[4], q3[4];
#pragma unroll
        for (int k = 0; k < 4; ++k) {
            int r = rg + 32 * k;
            float4 mv = mrowS[buf][r];
            int d = r - k0;
            float a = mv.x * inv0;
            if (d == 0) a = 0.f;
            float b2 = (mv.y - a * p01) * inv1;
            if (d == 1) b2 = 0.f;
            float c2 = (mv.z - a * p02 - b2 * p12) * inv2;
            if (d == 2) c2 = 0.f;
            float e2 = (mv.w - a * p03 - b2 * p13 - c2 * p23) * inv3;
            if (d == 3) e2 = 0.f;
            q0[k] = a; q1[k] = b2; q2[k] = c2; q3[k] = e2;
        }
        const float4* w0 = (const float4*)&praw[buf][0][0];
        const float4* w1 = (const float4*)&praw[buf][1][0];
        const float4* w2 = (const float4*)&praw[buf][2][0];
        const float4* w3 = (const float4*)&praw[buf][3][0];
#pragma unroll
        for (int j = 0; j < 4; ++j) {
            int g = seg + 16 * j;
            float4 a0 = w0[g], a1 = w1[g], a2 = w2[g], a3 = w3[g];
            float4 p1v = f4ms(a1, m1, a0);
            float4 p2v = f4ms(f4ms(a2, m2, a0), m2b, p1v);
            float4 p3v = f4ms(f4ms(f4ms(a3, m3, a0), m3b, p1v), m3c, p2v);
#pragma unroll
            for (int k = 0; k < 4; ++k) {
                float4 acc = R[k][j];
                acc = f4ms(acc, q0[k], a0);
                acc = f4ms(acc, q1[k], p1v);
                acc = f4ms(acc, q2[k], p2v);
                acc = f4ms(acc, q3[k], p3v);
                R[k][j] = acc;
            }
        }
        if (wd < 31) {
#pragma unroll
            for (int k = 0; k < 4; ++k) {
                int r = rg + 32 * k;
                int d2 = r - (k0 + 4);
                if (d2 >= 0 && d2 < 4) {
                    float4* dst = (float4*)&praw[buf ^ 1][d2][0];
                    dst[seg]      = R[k][0];
                    dst[seg + 16] = R[k][1];
                    dst[seg + 32] = R[k][2];
                    dst[seg + 48] = R[k][3];
                }
            }
            if (seg == ((wd + 1) & 15)) {
#pragma unroll
                for (int k = 0; k < 4; ++k) {
                    float4 sel = ((wd + 1) < 16) ? R[k][0] : R[k][1];
                    mrowS[buf ^ 1][rg + 32 * k] = sel;
                }
            }
        }
        __syncthreads();
        buf ^= 1;
    }

#pragma unroll
    for (int k = 0; k < 4; ++k) {
        int r = rg + 32 * k;
        float s = 1.0f / pivarr[r];
        float4* dst = (float4*)(A + (size_t)r * NX);
        float4 v2 = R[k][2];
        v2.x *= s; v2.y *= s; v2.z *= s; v2.w *= s;
        dst[seg] = v2;
        float4 v3 = R[k][3];
        v3.x *= s; v3.y *= s; v3.z *= s; v3.w *= s;
        dst[seg + 16] = v3;
    }
}

/* ---- K3: batched small matmuls, COLUMN-TILED grid (R19-verified) ---- */
struct MMDesc { const float* X; const float* Y; float* Z; int N; int ldX; int ldY; int ldZ; int Mrows; };
struct MMB { MMDesc d[4]; };
__global__ __launch_bounds__(128) void mmb_kernel(MMB mm) {
    MMDesc d = mm.d[blockIdx.y];
    if (d.Z == nullptr) return;
    int nct = (d.N + 127) >> 7;
    int i = blockIdx.x / nct;
    int jt = blockIdx.x - i * nct;
    if (i >= d.Mrows) return;
    int j = jt * 128 + threadIdx.x;
    if (j >= d.N) return;
    if (d.Y == nullptr) {
        d.Z[(size_t)i * d.ldZ + j] = d.X[(size_t)i * d.ldX + j];
        return;
    }
    const float* xr = d.X + (size_t)i * d.ldX;
    float a0 = 0.f, a1 = 0.f, a2 = 0.f, a3 = 0.f;
    for (int m = 0; m < 128; m += 4) {
        a0 += xr[m]     * d.Y[(size_t)(m)     * d.ldY + j];
        a1 += xr[m + 1] * d.Y[(size_t)(m + 1) * d.ldY + j];
        a2 += xr[m + 2] * d.Y[(size_t)(m + 2) * d.ldY + j];
        a3 += xr[m + 3] * d.Y[(size_t)(m + 3) * d.ldY + j];
    }
    d.Z[(size_t)i * d.ldZ + j] = (a0 + a1) + (a2 + a3);
}

/* ---- K3b (fused): blocks 0..511 -> WT2 assemble; 512.. -> WF bf16 split ---- */
__global__ __launch_bounds__(576) void wcvt_kernel(const float* __restrict__ Dm,
                                                   const float* __restrict__ C,
                                                   const float* __restrict__ Pm,
                                                   unsigned short* __restrict__ WT,
                                                   const float* __restrict__ WF,
                                                   unsigned short* __restrict__ WBH,
                                                   unsigned short* __restrict__ WBL,
                                                   int n4) {
    int blk = blockIdx.x;
    if (blk < 512) {
        int o = blk;
        int f = threadIdx.x;
        int k = o >> 6, yi = o & 63;
        float v = 0.f;
        if (f < 128) {
            v = (k == 0) ? C[(size_t)yi * NX + f]
                         : Dm[(size_t)(k - 1) * 64 * NX + (size_t)yi * NX + f];
        } else {
            int j = (f - 128) >> 6, e = (f - 128) & 63;
            if (k > j) v = Pm[(size_t)(k - 1 - j) * 64 * 64 + (size_t)yi * 64 + e];
        }
        WT[(size_t)o * 576 + f] = f2bf(v);
    } else {
        size_t idx = (size_t)(blk - 512) * 576 + threadIdx.x;
        if (idx < (size_t)n4) cvt_one(WF, WBH, WBL, idx);
    }
}

/* ---- K4 (fused): blocks 0..255 L-GEMM K-split x8; 256..511 v8-GEMM ---- */
__global__ __launch_bounds__(256) void lvgemm_kernel(const unsigned short* __restrict__ UH,
                                                     const unsigned short* __restrict__ UL,
                                                     const unsigned short* __restrict__ WH,
                                                     const unsigned short* __restrict__ WL,
                                                     float* __restrict__ Lp,
                                                     float* __restrict__ V8) {
    int t = threadIdx.x;
    int w = t >> 6, l = t & 63;
    int l16 = l & 15, l4 = l >> 4;
    int o0 = w * 32 + l16;
    f32x4 acc[4][2];
#pragma unroll
    for (int mt = 0; mt < 4; ++mt)
#pragma unroll
        for (int nt = 0; nt < 2; ++nt) acc[mt][nt] = (f32x4){0.f, 0.f, 0.f, 0.f};

    if (blockIdx.x < 256) {
        int blk = blockIdx.x & 31;
        int kblk = blockIdx.x >> 5;
        size_t uoff[4];
#pragma unroll
        for (int mt = 0; mt < 4; ++mt) {
            int pair = blk * 64 + mt * 16 + l16;
            int b = pair & 31, c = pair >> 5;
            uoff[mt] = ((size_t)b * T_LEN + (size_t)c * KCH) * NU;
        }
        int kt0 = kblk * (128 / KSPLIT);
        for (int kt = kt0; kt < kt0 + 128 / KSPLIT; ++kt) {
            int feat = kt * 32 + l4 * 8;
            bf16x8 ah[4], al[4], bh[2], bl[2];
#pragma unroll
            for (int mt = 0; mt < 4; ++mt) {
                ah[mt] = *(const bf16x8*)(UH + uoff[mt] + feat);
                al[mt] = *(const bf16x8*)(UL + uoff[mt] + feat);
            }
#pragma unroll
            for (int nt = 0; nt < 2; ++nt) {
                size_t woff = (size_t)(o0 + nt * 16) * 4096 + feat;
                bh[nt] = *(const bf16x8*)(WH + woff);
                bl[nt] = *(const bf16x8*)(WL + woff);
            }
#pragma unroll
            for (int mt = 0; mt < 4; ++mt)
#pragma unroll
                for (int nt = 0; nt < 2; ++nt) {
                    acc[mt][nt] = __builtin_amdgcn_mfma_f32_16x16x32_bf16(
                        ah[mt], bh[nt], acc[mt][nt], 0, 0, 0);
                    acc[mt][nt] = __builtin_amdgcn_mfma_f32_16x16x32_bf16(
                        ah[mt], bl[nt], acc[mt][nt], 0, 0, 0);
                    acc[mt][nt] = __builtin_amdgcn_mfma_f32_16x16x32_bf16(
                        al[mt], bh[nt], acc[mt][nt], 0, 0, 0);
                }
        }
        float* lout = Lp + (size_t)kblk * 2048 * NX;
#pragma unroll
        for (int mt = 0; mt < 4; ++mt)
#pragma unroll
            for (int nt = 0; nt < 2; ++nt)
#pragma unroll
                for (int reg = 0; reg < 4; ++reg) {
                    int r = blk * 64 + mt * 16 + l4 * 4 + reg;
                    lout[(size_t)r * NX + o0 + nt * 16] = acc[mt][nt][reg];
                }
    } else {
        int blk = blockIdx.x - 256;
        size_t uoff[4];
#pragma unroll
        for (int mt = 0; mt < 4; ++mt) {
            int r = blk * 64 + mt * 16 + l16;
            int pair = r >> 3, q = r & 7;
            int b = pair & 31, c = pair >> 5;
            uoff[mt] = ((size_t)b * T_LEN + (size_t)c * KCH + (size_t)q * 8) * NU;
        }
#pragma unroll 2
        for (int kt = 0; kt < 16; ++kt) {
            int feat = kt * 32 + l4 * 8;
            bf16x8 ah[4], al[4], bh[2], bl[2];
#pragma unroll
            for (int mt = 0; mt < 4; ++mt) {
                ah[mt] = *(const bf16x8*)(UH + uoff[mt] + feat);
                al[mt] = *(const bf16x8*)(UL + uoff[mt] + feat);
            }
#pragma unroll
            for (int nt = 0; nt < 2; ++nt) {
                size_t woff = (size_t)(o0 + nt * 16) * 4096 + 3584 + feat;
                bh[nt] = *(const bf16x8*)(WH + woff);
                bl[nt] = *(const bf16x8*)(WL + woff);
            }
#pragma unroll
            for (int mt = 0; mt < 4; ++mt)
#pragma unroll
                for (int nt = 0; nt < 2; ++nt) {
                    acc[mt][nt] = __builtin_amdgcn_mfma_f32_16x16x32_bf16(
                        ah[mt], bh[nt], acc[mt][nt], 0, 0, 0);
                    acc[mt][nt] = __builtin_amdgcn_mfma_f32_16x16x32_bf16(
                        ah[mt], bl[nt], acc[mt][nt], 0, 0, 0);
                    acc[mt][nt] = __builtin_amdgcn_mfma_f32_16x16x32_bf16(
                        al[mt], bh[nt], acc[mt][nt], 0, 0, 0);
                }
        }
#pragma unroll
        for (int mt = 0; mt < 4; ++mt)
#pragma unroll
            for (int nt = 0; nt < 2; ++nt)
#pragma unroll
                for (int reg = 0; reg < 4; ++reg) {
                    int r = blk * 64 + mt * 16 + l4 * 4 + reg;
                    V8[(size_t)r * NX + o0 + nt * 16] = acc[mt][nt][reg];
                }
    }
}

/* ---- K5: phase 2 with inline Lp reduce ---- */
__global__ __launch_bounds__(128) void phase2_kernel(const float* __restrict__ AK,
                                                     const float* __restrict__ Lp,
                                                     const float* __restrict__ x0,
                                                     float* __restrict__ Xc) {
    __shared__ float Ks[NX][NX + 1];
    __shared__ float xs[NX];
    int tid = threadIdx.x, b = blockIdx.x;
    for (int idx = tid; idx < NX * NX; idx += 128)
        Ks[idx >> 7][idx & 127] = AK[idx];
    float x = x0[tid];
    xs[tid] = x;
    Xc[(size_t)(0 * BATCH + b) * NX + tid] = x;
    __syncthreads();
    for (int c = 0; c < NC - 1; ++c) {
        size_t lidx = ((size_t)c * BATCH + b) * NX + tid;
        float lsum = 0.f;
#pragma unroll
        for (int k = 0; k < KSPLIT; ++k) lsum += Lp[(size_t)k * 2048 * NX + lidx];
        float a0 = 0.f, a1 = 0.f, a2 = 0.f, a3 = 0.f;
        for (int j = 0; j < NX; j += 4) {
            a0 += Ks[tid][j]     * xs[j];
            a1 += Ks[tid][j + 1] * xs[j + 1];
            a2 += Ks[tid][j + 2] * xs[j + 2];
            a3 += Ks[tid][j + 3] * xs[j + 3];
        }
        float xn = (a0 + a1) + (a2 + a3) + lsum;
        __syncthreads();
        xs[tid] = xn;
        Xc[((size_t)(c + 1) * BATCH + b) * NX + tid] = xn;
        __syncthreads();
    }
}

/* ---- fallback phase2 (reads plain L) ---- */
__global__ __launch_bounds__(128) void phase2fb_kernel(const float* __restrict__ AK,
                                                       const float* __restrict__ L,
                                                       const float* __restrict__ x0,
                                                       float* __restrict__ Xc) {
    __shared__ float Ks[NX][NX + 1];
    __shared__ float xs[NX];
    int tid = threadIdx.x, b = blockIdx.x;
    for (int idx = tid; idx < NX * NX; idx += 128)
        Ks[idx >> 7][idx & 127] = AK[idx];
    float x = x0[tid];
    xs[tid] = x;
    Xc[(size_t)(0 * BATCH + b) * NX + tid] = x;
    __syncthreads();
    for (int c = 0; c < NC - 1; ++c) {
        float a0 = 0.f, a1 = 0.f, a2 = 0.f, a3 = 0.f;
        for (int j = 0; j < NX; j += 4) {
            a0 += Ks[tid][j]     * xs[j];
            a1 += Ks[tid][j + 1] * xs[j + 1];
            a2 += Ks[tid][j + 2] * xs[j + 2];
            a3 += Ks[tid][j + 3] * xs[j + 3];
        }
        float xn = (a0 + a1) + (a2 + a3) + L[((size_t)c * BATCH + b) * NX + tid];
        __syncthreads();
        xs[tid] = xn;
        Xc[((size_t)(c + 1) * BATCH + b) * NX + tid] = xn;
        __syncthreads();
    }
}

/* ---- K6: chain8 — z <- A8 z + v8[q], 8 iters; emits x_{8q} bf16 ---- */
__global__ __launch_bounds__(256, 4) void chain8_kernel(const float* __restrict__ A8,
                                                        const float* __restrict__ V8,
                                                        const float* __restrict__ Xc,
                                                        unsigned short* __restrict__ X8) {
    int t = threadIdx.x;
    int g = t >> 3, seg = t & 7;
    int pair = blockIdx.x;

    float4 A8r[4][4];
#pragma unroll
    for (int r = 0; r < 4; ++r) {
        const float4* ap = (const float4*)(A8 + (size_t)(g + 32 * r) * NX + seg * 16);
        A8r[r][0] = ap[0]; A8r[r][1] = ap[1]; A8r[r][2] = ap[2]; A8r[r][3] = ap[3];
    }

    __shared__ __align__(16) float xs[2][192];
    __shared__ float vs[2][128];
    float vreg = 0.f;
    if (t < NX) {
        xs[0][XP(t)] = Xc[(size_t)pair * NX + t];
        vreg = V8[((size_t)pair * 8) * NX + t];
    }

    int buf = 0;
    for (int m = 0; m < 8; ++m) {
        if (t < NX) vs[buf][t] = vreg;
        if (t < NX && m < 7) vreg = V8[((size_t)pair * 8 + m + 1) * NX + t];
        __syncthreads();
        if (t < NX) X8[((size_t)pair * 8 + m) * NX + t] = f2bf(xs[buf][XP(t)]);
        const float4* xq0 = (const float4*)&xs[buf][seg * 24];
        const float4* xq1 = (const float4*)&xs[buf][seg * 24 + 12];
        float4 x0 = xq0[0], x1 = xq0[1], x2 = xq1[0], x3 = xq1[1];
        float acc[4];
#pragma unroll
        for (int r = 0; r < 4; ++r) {
            acc[r] = (f4dot(A8r[r][0], x0) + f4dot(A8r[r][1], x1))
                   + (f4dot(A8r[r][2], x2) + f4dot(A8r[r][3], x3));
        }
#pragma unroll
        for (int d = 1; d <= 4; d <<= 1) {
#pragma unroll
            for (int r = 0; r < 4; ++r) acc[r] += __shfl_xor(acc[r], d);
        }
        if (seg == 0) {
            xs[buf ^ 1][XP(g)]      = acc[0] + vs[buf][g];
            xs[buf ^ 1][XP(g + 32)] = acc[1] + vs[buf][g + 32];
            xs[buf ^ 1][XP(g + 64)] = acc[2] + vs[buf][g + 64];
            xs[buf ^ 1][XP(g + 96)] = acc[3] + vs[buf][g + 96];
        }
        buf ^= 1;
    }
}

/* ---- K7: MFMA y-emit (stride 8) ---- */
__global__ __launch_bounds__(512) void yemit_mfma_kernel(const unsigned short* __restrict__ X8,
                                                         const unsigned short* __restrict__ ub,
                                                         const unsigned short* __restrict__ WT,
                                                         float* __restrict__ y) {
    int t = threadIdx.x;
    int w = t >> 6, l = t & 63;
    int l16 = l & 15, l4 = l >> 4;
    int blk = blockIdx.x;
    f32x4 acc[4][4];
#pragma unroll
    for (int mt = 0; mt < 4; ++mt)
#pragma unroll
        for (int nt = 0; nt < 4; ++nt) acc[mt][nt] = (f32x4){0.f, 0.f, 0.f, 0.f};
    int grow[4];
    const unsigned short* ubase[4];
#pragma unroll
    for (int mt = 0; mt < 4; ++mt) {
        grow[mt] = blk * 64 + mt * 16 + l16;
        int pair = grow[mt] >> 3, q = grow[mt] & 7;
        int b = pair & 31, cc = pair >> 5;
        ubase[mt] = ub + ((size_t)b * T_LEN + (size_t)cc * KCH + (size_t)q * 8) * NU;
    }
#pragma unroll 2
    for (int kt = 0; kt < 18; ++kt) {
        int feat = kt * 32 + l4 * 8;
        bf16x8 afr[4];
#pragma unroll
        for (int mt = 0; mt < 4; ++mt) {
            const unsigned short* ap;
            if (feat < 128) ap = X8 + (size_t)grow[mt] * NX + feat;
            else            ap = ubase[mt] + (feat - 128);
            afr[mt] = *(const bf16x8*)ap;
        }
        bf16x8 bfr[4];
#pragma unroll
        for (int nt = 0; nt < 4; ++nt) {
            int o = w * 64 + nt * 16 + l16;
            bfr[nt] = *(const bf16x8*)(WT + (size_t)o * 576 + feat);
        }
#pragma unroll
        for (int mt = 0; mt < 4; ++mt)
#pragma unroll
            for (int nt = 0; nt < 4; ++nt)
                acc[mt][nt] = __builtin_amdgcn_mfma_f32_16x16x32_bf16(
                    afr[mt], bfr[nt], acc[mt][nt], 0, 0, 0);
    }
#pragma unroll
    for (int mt = 0; mt < 4; ++mt) {
#pragma unroll
        for (int nt = 0; nt < 4; ++nt) {
            int o = w * 64 + nt * 16 + l16;
            int k = o >> 6, yi = o & 63;
#pragma unroll
            for (int reg = 0; reg < 4; ++reg) {
                int r = blk * 64 + mt * 16 + l4 * 4 + reg;
                int pair = r >> 3, q = r & 7;
                int b = pair & 31, cc = pair >> 5;
                int tt = cc * KCH + q * 8 + k;
                y[((size_t)b * T_LEN + tt) * NY + yi] = acc[mt][nt][reg];
            }
        }
    }
}

/* ---- fallback path kernels (ws too small) ---- */
__global__ __launch_bounds__(512, 4) void phase1_kernel(const float* __restrict__ u_,
                                                        const float* __restrict__ A4,
                                                        const float* __restrict__ G,
                                                        float* __restrict__ L) {
    int t = threadIdx.x;
    int g = t >> 4, seg = t & 15;
    int pair = blockIdx.x;
    int c = pair >> 5, b = pair & 31;
    const float* urow = u_ + ((size_t)b * T_LEN + (size_t)c * KCH) * NU;
    float4 A4r[4][2], Gr[4][4];
#pragma unroll
    for (int r = 0; r < 4; ++r) {
        const float4* ap = (const float4*)(A4 + (size_t)(g + 32 * r) * NX + seg * 8);
        A4r[r][0] = ap[0]; A4r[r][1] = ap[1];
        const float4* gp = (const float4*)(G + (size_t)(g + 32 * r) * 256 + seg * 16);
        Gr[r][0] = gp[0]; Gr[r][1] = gp[1]; Gr[r][2] = gp[2]; Gr[r][3] = gp[3];
    }
    __shared__ __align__(16) float xs[2][192];
    __shared__ __align__(16) float us[2][320];
    if (t < NX) xs[0][XP(t)] = 0.f;
    float up = (t < 256) ? urow[t] : 0.f;
    int buf = 0;
    for (int m = 0; m < 16; ++m) {
        if (t < 256) us[buf][UP16(t)] = up;
        if (t < 256 && m < 15) up = urow[(size_t)(m + 1) * 256 + t];
        __syncthreads();
        const float4* xq = (const float4*)&xs[buf][seg * 12];
        float4 xa = xq[0], xb = xq[1];
        const float4* uq = (const float4*)&us[buf][seg * 20];
        float acc0[4], acc1[4];
#pragma unroll
        for (int r = 0; r < 4; ++r) {
            acc0[r] = f4dot(A4r[r][0], xa);
            acc1[r] = f4dot(A4r[r][1], xb);
        }
#pragma unroll
        for (int q = 0; q < 4; ++q) {
            float4 uv = uq[q];
#pragma unroll
            for (int r = 0; r < 4; ++r) {
                float pr = f4dot(Gr[r][q], uv);
                if (q & 1) acc1[r] += pr; else acc0[r] += pr;
            }
        }
        float acc[4];
#pragma unroll
        for (int r = 0; r < 4; ++r) acc[r] = acc0[r] + acc1[r];
#pragma unroll
        for (int d = 1; d <= 8; d <<= 1) {
#pragma unroll
            for (int r = 0; r < 4; ++r) acc[r] += __shfl_xor(acc[r], d);
        }
        if (seg == 0) {
            xs[buf ^ 1][XP(g)]      = acc[0];
            xs[buf ^ 1][XP(g + 32)] = acc[1];
            xs[buf ^ 1][XP(g + 64)] = acc[2];
            xs[buf ^ 1][XP(g + 96)] = acc[3];
        }
        buf ^= 1;
    }
    __syncthreads();
    if (t < NX) L[(size_t)pair * NX + t] = xs[buf][XP(t)];
}

__global__ __launch_bounds__(256) void phase3_fb_kernel(const float* __restrict__ u_,
                                                        const float* __restrict__ A,
                                                        const float* __restrict__ Bm,
                                                        const float* __restrict__ C,
                                                        const float* __restrict__ Xc,
                                                        float* __restrict__ y) {
    int t = threadIdx.x;
    int i = t >> 1, h = t & 1;
    int r = t >> 2, q = t & 3;
    int pair = blockIdx.x;
    int c = pair >> 5, b = pair & 31;
    const float* urow = u_ + ((size_t)b * T_LEN + (size_t)c * KCH) * NU;
    float* yrow = y + ((size_t)b * T_LEN + (size_t)c * KCH) * NY;
    float Ar[64];
    {
        const float4* Arow = (const float4*)(A + (size_t)i * NX + h * 64);
#pragma unroll
        for (int j4 = 0; j4 < 16; ++j4) {
            float4 v = Arow[j4];
            Ar[4 * j4] = v.x; Ar[4 * j4 + 1] = v.y; Ar[4 * j4 + 2] = v.z; Ar[4 * j4 + 3] = v.w;
        }
    }
    float Br[32];
    {
        const float4* Brow = (const float4*)(Bm + (size_t)i * NU + h * 32);
#pragma unroll
        for (int j4 = 0; j4 < 8; ++j4) {
            float4 v = Brow[j4];
            Br[4 * j4] = v.x; Br[4 * j4 + 1] = v.y; Br[4 * j4 + 2] = v.z; Br[4 * j4 + 3] = v.w;
        }
    }
    float Cr[32];
    {
        const float4* Crow = (const float4*)(C + (size_t)r * NX + q * 32);
#pragma unroll
        for (int j4 = 0; j4 < 8; ++j4) {
            float4 v = Crow[j4];
            Cr[4 * j4] = v.x; Cr[4 * j4 + 1] = v.y; Cr[4 * j4 + 2] = v.z; Cr[4 * j4 + 3] = v.w;
        }
    }
    __shared__ float xs[2][NX];
    __shared__ float us[2][NU];
    if (h == 0) xs[0][i] = Xc[(size_t)pair * NX + i];
    float up = (t < NU) ? urow[t] : 0.f;
    __syncthreads();
    {
        float c0 = 0.f, c1 = 0.f, c2 = 0.f, c3 = 0.f;
        const float* xp = &xs[0][q * 32];
#pragma unroll
        for (int j = 0; j < 32; j += 4) {
            c0 += Cr[j]     * xp[j];
            c1 += Cr[j + 1] * xp[j + 1];
            c2 += Cr[j + 2] * xp[j + 2];
            c3 += Cr[j + 3] * xp[j + 3];
        }
        float s = (c0 + c1) + (c2 + c3);
        s += __shfl_xor(s, 1);
        s += __shfl_xor(s, 2);
        if (q == 0) yrow[r] = s;
    }
    int buf = 0;
    for (int k = 1; k < KCH; ++k) {
        if (t < NU) us[buf][t] = up;
        if (k < KCH - 1 && t < NU) up = urow[(size_t)k * NU + t];
        __syncthreads();
        float a0 = 0.f, a1 = 0.f, a2 = 0.f, a3 = 0.f;
        const float* xp = &xs[buf][h * 64];
        const float* upp = &us[buf][h * 32];
#pragma unroll
        for (int j = 0; j < 64; j += 4) {
            a0 += Ar[j]     * xp[j];
            a1 += Ar[j + 1] * xp[j + 1];
            a2 += Ar[j + 2] * xp[j + 2];
            a3 += Ar[j + 3] * xp[j + 3];
        }
#pragma unroll
        for (int j = 0; j < 32; j += 4) {
            a0 += Br[j]     * upp[j];
            a1 += Br[j + 1] * upp[j + 1];
            a2 += Br[j + 2] * upp[j + 2];
            a3 += Br[j + 3] * upp[j + 3];
        }
        float a = (a0 + a1) + (a2 + a3);
        float s = a + __shfl_xor(a, 1);
        if (h == 0) xs[buf ^ 1][i] = s;
        __syncthreads();
        float c0 = 0.f, c1 = 0.f, c2 = 0.f, c3 = 0.f;
        const float* xcp = &xs[buf ^ 1][q * 32];
#pragma unroll
        for (int j = 0; j < 32; j += 4) {
            c0 += Cr[j]     * xcp[j];
            c1 += Cr[j + 1] * xcp[j + 1];
            c2 += Cr[j + 2] * xcp[j + 2];
            c3 += Cr[j + 3] * xcp[j + 3];
        }
        float sy = (c0 + c1) + (c2 + c3);
        sy += __shfl_xor(sy, 1);
        sy += __shfl_xor(sy, 2);
        if (q == 0) yrow[(size_t)k * NY + r] = sy;
        buf ^= 1;
    }
}

extern "C" void kernel_launch(void* const* d_in, const int* in_sizes, int n_in,
                              void* d_out, int out_size, void* d_ws, size_t ws_size,
                              hipStream_t stream) {
    const float* u_  = (const float*)d_in[0];
    const float* M   = (const float*)d_in[1];
    const float* Bm  = (const float*)d_in[2];
    const float* C   = (const float*)d_in[3];
    const float* x0  = (const float*)d_in[4];
    float* y = (float*)d_out;
    float* ws = (float*)d_ws;

    float* E   = ws + OFF_E;
    float* F   = ws + OFF_F;
    float* A   = ws + OFF_A;
    float* A2  = ws + OFF_E;
    float* A4  = ws + OFF_F;
    float* G   = ws + OFF_G;
    float* A8  = ws + OFF_A8;
    float* A16 = ws + OFF_A16;
    float* A32 = ws + OFF_A32;
    float* A64 = ws + OFF_A64;
    float* Dm  = ws + OFF_D;
    float* Pm  = ws + OFF_P;
    unsigned short* WT  = (unsigned short*)(ws + OFF_WT);
    float* WF  = ws + OFF_WF;
    unsigned short* WBH = (unsigned short*)(ws + OFF_WBH);
    unsigned short* WBL = (unsigned short*)(ws + OFF_WBL);
    float* Xc  = ws + OFF_XC;
    float* L   = ws + OFF_L;
    float* V8  = ws + OFF_V8;
    unsigned short* X8  = (unsigned short*)(ws + OFF_X8);
    unsigned short* UBH = (unsigned short*)(ws + OFF_UBH);
    unsigned short* UBL = (unsigned short*)(ws + OFF_UBL);
    float* Lp  = ws + OFF_LP;

    bool fast = ws_size >= (size_t)WS_NEED_FLOATS * sizeof(float);
    int n4 = BATCH * T_LEN * NU / 4;

    ef_kernel<<<256, 128, 0, stream>>>(M, E, F);
    solvecvt_kernel<<<fast ? 257 : 1, 512, 0, stream>>>(
        E, F, A, u_, fast ? UBH : nullptr, UBL, n4);

    if (fast) {
        /* L1: A2=A*A; D1=C*A; P0=C*B; WF[63]=B */
        { MMB mm;
          mm.d[0] = { A, A,  A2,          128, NX, NX, NX,  128 };
          mm.d[1] = { C, A,  Dm,          128, NX, NX, NX,  64  };
          mm.d[2] = { C, Bm, Pm,           64, NX, NU, 64,  64  };
          mm.d[3] = { Bm, nullptr, WF + 4032, 64, NU, 0, 4096, 128 };
          mmb_kernel<<<dim3(128, 4), 128, 0, stream>>>(mm); }
        /* L2: A4=A2*A2; D2=D1*A; P1=D1*B; WF[62]=A*WF[63] */
        { MMB mm;
          mm.d[0] = { A2, A2, A4,          128, NX, NX, NX,  128 };
          mm.d[1] = { Dm, A,  Dm + 8192,   128, NX, NX, NX,  64  };
          mm.d[2] = { Dm, Bm, Pm + 4096,    64, NX, NU, 64,  64  };
          mm.d[3] = { A, WF + 4032, WF + 3968, 64, NX, 4096, 4096, 128 };
          mmb_kernel<<<dim3(128, 4), 128, 0, stream>>>(mm); }
        /* L3: A8=A4*A4; D3=D2*A; P2=D2*B; WF[60..61]=A2*WF[62..63] */
        { MMB mm;
          mm.d[0] = { A4, A4, A8,              128, NX, NX, NX,  128 };
          mm.d[1] = { Dm + 8192, A, Dm + 16384, 128, NX, NX, NX, 64  };
          mm.d[2] = { Dm + 8192, Bm, Pm + 8192,  64, NX, NU, 64, 64  };
          mm.d[3] = { A2, WF + 3968, WF + 3840, 128, NX, 4096, 4096, 128 };
          mmb_kernel<<<dim3(256, 4), 128, 0, stream>>>(mm); }
        /* L4: A16=A8*A8; D4=D2*A2; P3=D3*B; WF[56..59]=A4*WF[60..63] */
        { MMB mm;
          mm.d[0] = { A8, A8, A16,              128, NX, NX, NX,  128 };
          mm.d[1] = { Dm + 8192, A2, Dm + 24576, 128, NX, NX, NX, 64  };
          mm.d[2] = { Dm + 16384, Bm, Pm + 12288, 64, NX, NU, 64, 64  };
          mm.d[3] = { A4, WF + 3840, WF + 3584, 256, NX, 4096, 4096, 128 };
          mmb_kernel<<<dim3(256, 4), 128, 0, stream>>>(mm); }
        /* L5: A32=A16*A16; D5=D3*A2; P4=D4*B; WF[48..55]=A8*WF[56..63] */
        { MMB mm;
          mm.d[0] = { A16, A16, A32,             128, NX, NX, NX,  128 };
          mm.d[1] = { Dm + 16384, A2, Dm + 32768, 128, NX, NX, NX, 64  };
          mm.d[2] = { Dm + 24576, Bm, Pm + 16384,  64, NX, NU, 64, 64  };
          mm.d[3] = { A8, WF + 3584, WF + 3072, 512, NX, 4096, 4096, 128 };
          mmb_kernel<<<dim3(512, 4), 128, 0, stream>>>(mm); }
        /* L6: A64=A32*A32; D6=D2*A4; P5=D5*B; WF[32..47]=A16*WF[48..63] */
        { MMB mm;
          mm.d[0] = { A32, A32, A64,             128, NX, NX, NX,  128 };
          mm.d[1] = { Dm + 8192, A4, Dm + 40960,  128, NX, NX, NX, 64  };
          mm.d[2] = { Dm + 32768, Bm, Pm + 20480,  64, NX, NU, 64, 64  };
          mm.d[3] = { A16, WF + 3072, WF + 2048, 1024, NX, 4096, 4096, 128 };
          mmb_kernel<<<dim3(1024, 4), 128, 0, stream>>>(mm); }
        /* L7: WF[0..31]=A32*WF[32..63]; D7=D3*A4; P6=D6*B */
        { MMB mm;
          mm.d[0] = { A32, WF + 2048, WF, 2048, NX, 4096, 4096, 128 };
          mm.d[1] = { Dm + 16384, A4, Dm + 49152, 128, NX, NX, NX, 64 };
          mm.d[2] = { Dm + 40960, Bm, Pm + 24576,  64, NX, NU, 64, 64 };
          mm.d[3] = { nullptr, nullptr, nullptr, 0, 0, 0, 0, 0 };
          mmb_kernel<<<dim3(2048, 4), 128, 0, stream>>>(mm); }

        wcvt_kernel<<<512 + (NX * 4096 / 4 + 575) / 576, 576, 0, stream>>>(
            Dm, C, Pm, WT, WF, WBH, WBL, NX * 4096 / 4);
        lvgemm_kernel<<<512, 256, 0, stream>>>(UBH, UBL, WBH, WBL, Lp, V8);
        phase2_kernel<<<BATCH, 128, 0, stream>>>(A64, Lp, x0, Xc);
        chain8_kernel<<<NC * BATCH, 256, 0, stream>>>(A8, V8, Xc, X8);
        yemit_mfma_kernel<<<256, 512, 0, stream>>>(X8, UBH, WT, y);
    } else {
        { MMB mm;
          mm.d[0] = { A, A,  A2,       128, NX, NX, NX,  128 };
          mm.d[1] = { A, Bm, G + 128,   64, NX, NU, 256, 128 };
          mm.d[2] = { Bm, nullptr, G + 192, 64, NU, 0, 256, 128 };
          mm.d[3] = { nullptr, nullptr, nullptr, 0, 0, 0, 0, 0 };
          mmb_kernel<<<dim3(128, 4), 128, 0, stream>>>(mm); }
        { MMB mm;
          mm.d[0] = { A2, A2, A4,   128, NX, NX,  NX,  128 };
          mm.d[1] = { A2, G + 128, G, 128, NX, 256, 256, 128 };
          mm.d[2] = { nullptr, nullptr, nullptr, 0, 0, 0, 0, 0 };
          mm.d[3] = { nullptr, nullptr, nullptr, 0, 0, 0, 0, 0 };
          mmb_kernel<<<dim3(256, 4), 128, 0, stream>>>(mm); }
        { MMB mm;
          mm.d[0] = { A4, A4, A8,    128, NX, NX, NX, 128 };
          mm.d[1] = { nullptr, nullptr, nullptr, 0, 0, 0, 0, 0 };
          mm.d[2] = { nullptr, nullptr, nullptr, 0, 0, 0, 0, 0 };
          mm.d[3] = { nullptr, nullptr, nullptr, 0, 0, 0, 0, 0 };
          mmb_kernel<<<dim3(128, 4), 128, 0, stream>>>(mm); }
        { MMB mm;
          mm.d[0] = { A8, A8, A16,   128, NX, NX, NX, 128 };
          mm.d[1] = { nullptr, nullptr, nullptr, 0, 0, 0, 0, 0 };
          mm.d[2] = { nullptr, nullptr, nullptr, 0, 0, 0, 0, 0 };
          mm.d[3] = { nullptr, nullptr, nullptr, 0, 0, 0, 0, 0 };
          mmb_kernel<<<dim3(128, 4), 128, 0, stream>>>(mm); }
        { MMB mm;
          mm.d[0] = { A16, A16, A32, 128, NX, NX, NX, 128 };
          mm.d[1] = { nullptr, nullptr, nullptr, 0, 0, 0, 0, 0 };
          mm.d[2] = { nullptr, nullptr, nullptr, 0, 0, 0, 0, 0 };
          mm.d[3] = { nullptr, nullptr, nullptr, 0, 0, 0, 0, 0 };
          mmb_kernel<<<dim3(128, 4), 128, 0, stream>>>(mm); }
        { MMB mm;
          mm.d[0] = { A32, A32, A64, 128, NX, NX, NX, 128 };
          mm.d[1] = { nullptr, nullptr, nullptr, 0, 0, 0, 0, 0 };
          mm.d[2] = { nullptr, nullptr, nullptr, 0, 0, 0, 0, 0 };
          mm.d[3] = { nullptr, nullptr, nullptr, 0, 0, 0, 0, 0 };
          mmb_kernel<<<dim3(128, 4), 128, 0, stream>>>(mm); }
        phase1_kernel<<<NC * BATCH, 512, 0, stream>>>(u_, A4, G, L);
        phase2fb_kernel<<<BATCH, 128, 0, stream>>>(A64, L, x0, Xc);
        phase3_fb_kernel<<<NC * BATCH, 256, 0, stream>>>(u_, A, Bm, C, Xc, y);
    }
}